// Round 9
// baseline (205.867 us; speedup 1.0000x reference)
//
#include <hip/hip_runtime.h>
#include <hip/hip_fp16.h>

// b=2, c=64, 48x48 -> n=2304, heads=4, hd=16. n = 9*256 = 144*16.
// r26: 4-KERNEL pipeline (was 5). Evidence: total-minus-k_attn has been
// ~114-135us across r0-r25 while bottom-up GPU floors for the 4 small
// kernels sum to ~15-20us -> suspected per-kernel launch/drain boundary
// ~15-20us each. This round: (1) k_qkv+k_dw FUSED into k_qd (halo
// recompute of the 1x1 conv into LDS, bit-identical fma chains; kills a
// boundary + the qkv_raw 3.5MB round-trip); (2) k_ent2 at 1024 thr (the
// r25 restructure that won for k_attn); (3) k_attn_f: kmax/kmin SALU
// round-pruning (mask-exact, incl keep==2304 edge) + PV over 8 waves;
// (4) k_proj 576 blocks. k_attn history: latency-bound (r4-r7: hist-vs-
// ballot, conflicts, VGPR all null; tile size + wave count real).
// Decision rule: (totalD - k_attnD) >= 15us -> r27 = persistent fusion
// w/ spin barriers; <= 5us -> small kernels are real GPU time.

typedef _Float16 half8_t __attribute__((ext_vector_type(8)));
typedef float floatx4 __attribute__((ext_vector_type(4)));

#define LSTR 2328  // lg row stride in halves (4656B; 1164 dw = 12 mod 32)

union HU { unsigned short s; _Float16 h; };
__device__ __forceinline__ _Float16 ubits_h(unsigned short u) {
  HU c; c.s = u; return c.h;
}
// ascending 16-bit key -> the f16 value it encodes
__device__ __forceinline__ _Float16 key_h(unsigned k) {
  unsigned short u = (k & 0x8000u) ? (unsigned short)(k & 0x7FFFu)
                                   : (unsigned short)((~k) & 0xFFFFu);
  return ubits_h(u);
}

// K1: FUSED 1x1 conv + 3x3 depthwise. grid = 864 (chunk 9 x qtr 4 x
// sel 3 x head 4 x b 2), 256 thr. Computes qkv for 4 channels x 8-row
// window (incl. halo) directly into LDS (same fma chain as the old
// k_qkv -> bit-identical values), then the depthwise conv + q/k packed
// split stores. Also zeroes ent[].
__global__ __launch_bounds__(256) void k_qd(
    const float* __restrict__ x, const float* __restrict__ Wq,
    const float* __restrict__ bq, const float* __restrict__ Wpos,
    const float* __restrict__ bpos, _Float16* __restrict__ q2,
    _Float16* __restrict__ k2, _Float16* __restrict__ vt,
    float* __restrict__ ent) {
  __shared__ float smem[4][384];  // 4 ch x 8 rows x 48 = 6 KB
  if (blockIdx.x == 0 && threadIdx.x < 8) ent[threadIdx.x] = 0.f;
  int blk = blockIdx.x;
  int chunk = blk % 9;
  int qtr = (blk / 9) % 4;
  int sel = (blk / 36) % 3;
  int head = (blk / 108) % 4;
  int b = blk / 432;
  int chbase = sel * 64 + head * 16 + qtr * 4;
  int bh = b * 4 + head;
  int tid = threadIdx.x;
  int p0 = chunk * 256;
  int baserow = p0 / 48;
  int rA = min(max(baserow - 1, 0), 40);  // 8-row window within [0,47]

  // qkv = 1x1 conv, computed on the fly (6 values/thread)
  const float* xb = x + (size_t)b * 64 * 2304;
#pragma unroll
  for (int l = 0; l < 6; l++) {
    int idx = tid + l * 256;
    int ch = idx / 384;
    int off = idx - ch * 384;
    int pos2 = (rA + off / 48) * 48 + (off % 48);
    const float* wr = Wq + (chbase + ch) * 64;
    float a = bq[chbase + ch];
#pragma unroll
    for (int c = 0; c < 64; c++) a = fmaf(wr[c], xb[c * 2304 + pos2], a);
    smem[ch][off] = a;
  }
  __syncthreads();

  int pos = p0 + tid;
  int yy = pos / 48, xx = pos - yy * 48;
  int ry = yy - rA;
  float accv[4];
#pragma unroll
  for (int d = 0; d < 4; d++) {
    const float* w = Wpos + (chbase + d) * 9;
    float a = bpos[chbase + d];
#pragma unroll
    for (int dy = -1; dy <= 1; dy++) {
      int y2 = yy + dy;
      if ((unsigned)y2 < 48u) {
#pragma unroll
        for (int dx = -1; dx <= 1; dx++) {
          int x2 = xx + dx;
          if ((unsigned)x2 < 48u)
            a = fmaf(w[(dy + 1) * 3 + (dx + 1)], smem[d][(ry + dy) * 48 + x2],
                     a);
        }
      }
    }
    accv[d] = a;
  }

  if (sel == 2) {
#pragma unroll
    for (int d = 0; d < 4; d++)
      vt[((size_t)bh * 16 + qtr * 4 + d) * 2304 + pos] = (_Float16)accv[d];
  } else {
    _Float16 h1[4], h2[4];
#pragma unroll
    for (int d = 0; d < 4; d++) {
      float a = (sel == 0) ? accv[d] * 0.25f : accv[d];
      h1[d] = (_Float16)a;
      h2[d] = (_Float16)(a - (float)h1[d]);
    }
    _Float16* dst = ((sel == 0) ? q2 : k2) + ((size_t)bh * 2304 + pos) * 32;
    *(uint2*)(dst + qtr * 4) = *(uint2*)&h1[0];
    *(uint2*)(dst + 16 + qtr * 4) = *(uint2*)&h2[0];
  }
}

// K2: entropy via MFMA QK^T, 1024 thr (16 waves x 144-col strips --
// the r25 wave-count restructure). grid = 8*144. No logit store.
__global__ __launch_bounds__(1024) void k_ent2(const _Float16* __restrict__ q2,
                                               const _Float16* __restrict__ k2,
                                               float* __restrict__ ent) {
  __shared__ float sWv[16][16], uWv[16][16];
  int blk = blockIdx.x;
  int rowtile = blk % 144;
  int bh = blk / 144;
  int row0 = rowtile * 16;
  int tid = threadIdx.x, lane = tid & 63, wave = tid >> 6;
  int m16 = lane & 15, quad = lane >> 4;

  const half8_t* q2v =
      (const half8_t*)(q2 + ((size_t)bh * 2304 + row0 + m16) * 32);
  half8_t A1 = q2v[quad];
  half8_t zh = {};
  half8_t A2 = (lane < 32) ? A1 : zh;
  const half8_t* kbase = (const half8_t*)(k2 + (size_t)bh * 2304 * 32);

  // s = sum e^a, u = sum a e^a (entropy = log S - U/S; shift-invariant)
  float s[4] = {0.f, 0.f, 0.f, 0.f}, u[4] = {0.f, 0.f, 0.f, 0.f};
#pragma unroll 3
  for (int t = 0; t < 9; t++) {
    int col = wave * 144 + t * 16 + m16;
    const half8_t* kk = kbase + (size_t)col * 4;
    half8_t b1 = kk[quad & 1];
    half8_t b2 = kk[2 + (quad & 1)];
    floatx4 acc = {};
    acc = __builtin_amdgcn_mfma_f32_16x16x32_f16(A2, b2, acc, 0, 0, 0);
    acc = __builtin_amdgcn_mfma_f32_16x16x32_f16(A1, b1, acc, 0, 0, 0);
#pragma unroll
    for (int i = 0; i < 4; i++) {
      float e = __expf(acc[i]);
      s[i] += e;
      u[i] = fmaf(acc[i], e, u[i]);
    }
  }
#pragma unroll
  for (int off = 1; off < 16; off <<= 1) {
#pragma unroll
    for (int i = 0; i < 4; i++) {
      s[i] += __shfl_xor(s[i], off);
      u[i] += __shfl_xor(u[i], off);
    }
  }
  if (m16 == 0) {
#pragma unroll
    for (int i = 0; i < 4; i++) {
      sWv[wave][quad * 4 + i] = s[i];
      uWv[wave][quad * 4 + i] = u[i];
    }
  }
  __syncthreads();
  if (tid < 16) {
    float S = 0.f, U = 0.f;
#pragma unroll
    for (int w = 0; w < 16; w++) {
      S += sWv[w][tid];
      U += uWv[w][tid];
    }
    float er = __logf(S) - U / S;
    er += __shfl_xor(er, 1);
    er += __shfl_xor(er, 2);
    er += __shfl_xor(er, 4);
    er += __shfl_xor(er, 8);
    if (tid == 0) atomicAdd(&ent[bh], er);
  }
}

// K3: FUSED per-16-row-tile attention, 1024 thr (16 waves): QK^T MFMA
// (9 col-tiles/wave) -> LDS logit tile (stride 2328 halves) -> per-row
// top-k (ballot bit-search + kmax/kmin SALU round pruning, 1 row/wave)
// -> in-place masked exp -> PV MFMA (8 waves x 288-col strips) -> oh.
// grid = 1152 (bh = blk&7 XCD affinity). LDS 74.5KB, 2 blocks/CU.
__global__ __launch_bounds__(1024, 8) void k_attn_f(
    const _Float16* __restrict__ q2, const _Float16* __restrict__ k2,
    const _Float16* __restrict__ vt, const float* __restrict__ ent,
    const float* __restrict__ Wg1, const float* __restrict__ bg1,
    const float* __restrict__ Wg2, const float* __restrict__ bg2,
    float* __restrict__ oh) {
  __shared__ __align__(16) _Float16 lg[16 * LSTR];  // 74496 B
  __shared__ float sS[16];

  int blk = blockIdx.x;
  int bh = blk & 7;     // one bh per XCD -> q2/k2/vt slices L2-resident
  int tile = blk >> 3;  // 0..143
  int row0 = tile * 16;
  int tid = threadIdx.x, lane = tid & 63, wave = tid >> 6;
  int m16 = lane & 15, quad = lane >> 4;

  // ---- gate MLP (uniform) ----
  float eAvg = ent[bh] * (1.f / 2304.f);
  float gacc = bg2[0];
#pragma unroll
  for (int i = 0; i < 16; i++) {
    float h = fmaxf(fmaf(eAvg, Wg1[i], bg1[i]), 0.f);
    gacc = fmaf(h, Wg2[i], gacc);
  }
  float ratio = 0.9f / (1.f + __expf(-gacc)) + 0.1f;
  int kp = (int)ceilf(ratio * 2304.f);
  unsigned keep = (unsigned)min(max(kp, 1), 2304);

  // ---- phase 1: QK^T -> lg rows 0..15 (9 col-tiles per wave) ----
  {
    const half8_t* q2v =
        (const half8_t*)(q2 + ((size_t)bh * 2304 + row0 + m16) * 32);
    half8_t A1 = q2v[quad];
    half8_t zh = {};
    half8_t A2 = (lane < 32) ? A1 : zh;
    const half8_t* kbase = (const half8_t*)(k2 + (size_t)bh * 2304 * 32);
#pragma unroll 3
    for (int t = 0; t < 9; t++) {
      int col = wave * 144 + t * 16 + m16;
      const half8_t* kk = kbase + (size_t)col * 4;
      half8_t b1 = kk[quad & 1];
      half8_t b2 = kk[2 + (quad & 1)];
      floatx4 acc = {};
      acc = __builtin_amdgcn_mfma_f32_16x16x32_f16(A2, b2, acc, 0, 0, 0);
      acc = __builtin_amdgcn_mfma_f32_16x16x32_f16(A1, b1, acc, 0, 0, 0);
#pragma unroll
      for (int i = 0; i < 4; i++)
        lg[(quad * 4 + i) * LSTR + col] = (_Float16)acc[i];
    }
  }
  __syncthreads();

  // ---- phase 2: per-row top-k (ballot) + masked exp, 1 row/wave ----
  {
    int r = wave;
    char* rb = (char*)lg + (size_t)r * (LSTR * 2);
    const uint4* s4 = (const uint4*)rb;
    uint4 q0 = s4[lane];
    uint4 q1 = s4[lane + 64];
    uint4 q2r = s4[lane + 128];
    uint4 q3 = s4[lane + 192];
    uint2 q4 = *(const uint2*)(rb + 4096 + lane * 8);
    unsigned wb[18] = {q0.x, q0.y, q0.z, q0.w, q1.x, q1.y, q1.z, q1.w,
                       q2r.x, q2r.y, q2r.z, q2r.w, q3.x, q3.y, q3.z, q3.w,
                       q4.x, q4.y};
    // ascending-key transform (packed), then unpack to 36 u32 regs
    unsigned ku[36];
#pragma unroll
    for (int i = 0; i < 18; i++) {
      unsigned kbi =
          wb[i] ^ (((wb[i] >> 15) & 0x00010001u) * 0x7FFFu + 0x80008000u);
      ku[2 * i + 0] = kbi & 0xFFFFu;
      ku[2 * i + 1] = kbi >> 16;
    }

    // row key bounds -> SALU-only round pruning (mask-exact: cand>kmx
    // => cnt=0 (skip); cand<=kmn => cnt=2304>=keep (set, skip count) --
    // same final mask incl. keep==2304 edge since any T with cnt==keep
    // selects the identical element set)
    unsigned kmx = ku[0], kmn = ku[0];
#pragma unroll
    for (int i = 1; i < 36; i++) {
      kmx = max(kmx, ku[i]);
      kmn = min(kmn, ku[i]);
    }
#pragma unroll
    for (int off = 1; off < 64; off <<= 1) {
      kmx = max(kmx, (unsigned)__shfl_xor((int)kmx, off));
      kmn = min(kmn, (unsigned)__shfl_xor((int)kmn, off));
    }

    // exact k-th largest: 16-round ballot bit-search, no LDS traffic
    unsigned T = 0u;
    for (int bit = 15; bit >= 0; --bit) {
      unsigned cand = T | (1u << bit);
      if (cand > kmx) continue;
      if (cand <= kmn) { T = cand; continue; }
      unsigned cnt = 0u;
#pragma unroll
      for (int i = 0; i < 36; i++)
        cnt += (unsigned)__popcll(__ballot(ku[i] >= cand));
      if (cnt >= keep) {
        T = cand;  // uniform
        if (cnt == keep) break;
      }
    }
    _Float16 th_h = key_h(T);

    // masked exp, pack f16, write back in place (legacy sp pairing)
    float sp = 0.f;
    uint4* prow4 = (uint4*)rb;
#pragma unroll
    for (int g = 0; g < 4; g++) {
      uint4 o;
      unsigned ow[4];
#pragma unroll
      for (int wj = 0; wj < 4; wj++) {
        unsigned w = wb[g * 4 + wj];
        _Float16 hlo = ubits_h((unsigned short)(w & 0xFFFFu));
        _Float16 hhi = ubits_h((unsigned short)(w >> 16));
        float plo = (hlo >= th_h) ? __expf((float)hlo) : 0.f;
        float phi = (hhi >= th_h) ? __expf((float)hhi) : 0.f;
        __half2 hp = __floats2half2_rn(plo, phi);
        ow[wj] = *(unsigned*)&hp;
        if (wj == 0) sp += ((plo + phi));
      }
      // legacy pairing: ((p0+p1)+(p2+p3)) + ((p4+p5)+(p6+p7))
      o.x = ow[0]; o.y = ow[1]; o.z = ow[2]; o.w = ow[3];
      prow4[lane + g * 64] = o;
      {
        _Float16 h2a = ubits_h((unsigned short)(wb[g * 4 + 1] & 0xFFFFu));
        _Float16 h2b = ubits_h((unsigned short)(wb[g * 4 + 1] >> 16));
        _Float16 h3a = ubits_h((unsigned short)(wb[g * 4 + 2] & 0xFFFFu));
        _Float16 h3b = ubits_h((unsigned short)(wb[g * 4 + 2] >> 16));
        _Float16 h4a = ubits_h((unsigned short)(wb[g * 4 + 3] & 0xFFFFu));
        _Float16 h4b = ubits_h((unsigned short)(wb[g * 4 + 3] >> 16));
        float p2 = (h2a >= th_h) ? __expf((float)h2a) : 0.f;
        float p3 = (h2b >= th_h) ? __expf((float)h2b) : 0.f;
        float p4 = (h3a >= th_h) ? __expf((float)h3a) : 0.f;
        float p5 = (h3b >= th_h) ? __expf((float)h3b) : 0.f;
        float p6 = (h4a >= th_h) ? __expf((float)h4a) : 0.f;
        float p7 = (h4b >= th_h) ? __expf((float)h4b) : 0.f;
        sp += (p2 + p3);
        sp += (p4 + p5) + (p6 + p7);
      }
    }
    {
      _Float16 h0 = ubits_h((unsigned short)(wb[16] & 0xFFFFu));
      _Float16 h1 = ubits_h((unsigned short)(wb[16] >> 16));
      _Float16 h2 = ubits_h((unsigned short)(wb[17] & 0xFFFFu));
      _Float16 h3 = ubits_h((unsigned short)(wb[17] >> 16));
      float p0 = (h0 >= th_h) ? __expf((float)h0) : 0.f;
      float p1 = (h1 >= th_h) ? __expf((float)h1) : 0.f;
      float p2 = (h2 >= th_h) ? __expf((float)h2) : 0.f;
      float p3 = (h3 >= th_h) ? __expf((float)h3) : 0.f;
      sp += (p0 + p1) + (p2 + p3);
      uint2 o;
      __half2 hp0 = __floats2half2_rn(p0, p1); o.x = *(unsigned*)&hp0;
      __half2 hp1 = __floats2half2_rn(p2, p3); o.y = *(unsigned*)&hp1;
      *(uint2*)(rb + 4096 + lane * 8) = o;
    }
#pragma unroll
    for (int off = 1; off < 64; off <<= 1) sp += __shfl_xor(sp, off);
    if (lane == 0) sS[r] = sp;
  }
  __syncthreads();  // all rows' p visible; sS visible

  // ---- phase 3: PV via MFMA on waves 0-7 (8 x 288-col strips) ----
  floatx4 acc = {};
  if (wave < 8) {
    const _Float16* vrow = vt + ((size_t)bh * 16 + m16) * 2304;
    const _Float16* prow = lg + (size_t)m16 * LSTR;
    int jb0 = wave * 288 + quad * 8;
#pragma unroll 3
    for (int t = 0; t < 9; t++) {
      int jb = jb0 + t * 32;
      half8_t a2 = *(const half8_t*)&prow[jb];
      half8_t b2 = *(const half8_t*)&vrow[jb];
      acc = __builtin_amdgcn_mfma_f32_16x16x32_f16(a2, b2, acc, 0, 0, 0);
    }
  }
  __syncthreads();  // all lg reads done; safe to alias as reduction buf
  float* red = (float*)lg;
  if (wave < 8) {
#pragma unroll
    for (int i = 0; i < 4; i++)
      red[wave * 256 + (quad * 4 + i) * 16 + m16] = acc[i];
  }
  __syncthreads();
  if (tid < 256) {
    int r = tid >> 4;
    float s2 = ((red[0 * 256 + tid] + red[1 * 256 + tid]) +
                (red[2 * 256 + tid] + red[3 * 256 + tid])) +
               ((red[4 * 256 + tid] + red[5 * 256 + tid]) +
                (red[6 * 256 + tid] + red[7 * 256 + tid]));
    int d = tid & 15;
    oh[((size_t)(bh * 2304 + row0 + r)) * 16 + d] = s2 / sS[r];
  }
}

// K4: output projection, 2 output channels per block. grid = 2*32*9 = 576.
__global__ __launch_bounds__(256) void k_proj(const float* __restrict__ oh,
                                              const float* __restrict__ Wp,
                                              const float* __restrict__ bp,
                                              float* __restrict__ out) {
  int blk = blockIdx.x;
  int chunk = blk % 9;
  int cog = (blk / 9) % 32;
  int b = blk / 288;
  int co0 = cog * 2;
  int pos = chunk * 256 + threadIdx.x;
  float a0 = bp[co0 + 0], a1 = bp[co0 + 1];
#pragma unroll
  for (int head = 0; head < 4; head++) {
    const float4* op =
        (const float4*)(oh + ((size_t)((b * 4 + head) * 2304 + pos)) * 16);
#pragma unroll
    for (int p = 0; p < 4; p++) {
      float4 o4 = op[p];
#pragma unroll
      for (int i = 0; i < 2; i++) {
        const float* wr = Wp + (co0 + i) * 64 + head * 16 + p * 4;
        float* ai = (i == 0) ? &a0 : &a1;
        *ai = fmaf(wr[0], o4.x, *ai);
        *ai = fmaf(wr[1], o4.y, *ai);
        *ai = fmaf(wr[2], o4.z, *ai);
        *ai = fmaf(wr[3], o4.w, *ai);
      }
    }
  }
  out[(b * 64 + co0 + 0) * 2304 + pos] = a0;
  out[(b * 64 + co0 + 1) * 2304 + pos] = a1;
}

extern "C" void kernel_launch(void* const* d_in, const int* in_sizes, int n_in,
                              void* d_out, int out_size, void* d_ws,
                              size_t ws_size, hipStream_t stream) {
  const float* x    = (const float*)d_in[0];
  const float* Wqkv = (const float*)d_in[1];
  const float* bqkv = (const float*)d_in[2];
  const float* Wpos = (const float*)d_in[3];
  const float* bpos = (const float*)d_in[4];
  const float* Wg1  = (const float*)d_in[5];
  const float* bg1  = (const float*)d_in[6];
  const float* Wg2  = (const float*)d_in[7];
  const float* bg2  = (const float*)d_in[8];
  const float* Wpr  = (const float*)d_in[9];
  const float* bpr  = (const float*)d_in[10];
  float* out = (float*)d_out;

  // workspace (no qkv_raw, no logit cache)
  char* base = (char*)d_ws;
  float* oh = (float*)base;             // 294912 floats
  float* ent = oh + 294912;             // 8 floats
  _Float16* q2 = (_Float16*)(ent + 8);  // 589824 halves
  _Float16* k2 = q2 + 589824;           // 589824 halves
  _Float16* vt = k2 + 589824;           // 294912 halves (V^T f16 [bh][d][j])

  hipLaunchKernelGGL(k_qd, dim3(864), dim3(256), 0, stream,
                     x, Wqkv, bqkv, Wpos, bpos, q2, k2, vt, ent);
  hipLaunchKernelGGL(k_ent2, dim3(8 * 144), dim3(1024), 0, stream,
                     q2, k2, ent);
  hipLaunchKernelGGL(k_attn_f, dim3(1152), dim3(1024), 0, stream,
                     q2, k2, vt, ent, Wg1, bg1, Wg2, bg2, oh);
  hipLaunchKernelGGL(k_proj, dim3(576), dim3(256), 0, stream,
                     oh, Wpr, bpr, out);
}